// Round 7
// baseline (223.843 us; speedup 1.0000x reference)
//
#include <hip/hip_runtime.h>
#include <hip/hip_bf16.h>
#include <math.h>

// Problem constants
#define B_  4
#define L_  8192
#define D_  512

// MFMA GEMM tiling
#define BM   128
#define NCT  4                 // col tiles of 128
#define NRT  (L_ / BM)         // 64
#define NSTEP 16               // K = 512 / 32

// Scan chunking
#define CHUNK 64
#define NCHUNK (L_ / CHUNK)    // 128

#define MAXFIX 16380
#define FIX_TAU 1.0e-3f
#define FTILE 4                // borderline rows per fixup block

typedef short bf16x8 __attribute__((ext_vector_type(8)));
typedef float f32x4 __attribute__((ext_vector_type(4)));
typedef unsigned short u16;
typedef unsigned int u32;

__device__ __forceinline__ u16 f2bf_rne(float f) {
    unsigned u = __float_as_uint(f);
    unsigned r = (u + 0x7FFFu + ((u >> 16) & 1u)) >> 16;
    return (u16)r;
}

// packed fp32x2 -> bf16x2 (hardware v_cvt_pk_bf16_f32, RNE)
__device__ __forceinline__ u32 pk2(float lo, float hi) {
    __hip_bfloat162 v = __float22bfloat162_rn(float2{lo, hi});
    union { __hip_bfloat162 b; u32 u; } cv; cv.b = v;
    return cv.u;
}

__device__ __forceinline__ void store_chunk(u16* dst, float4 a, float4 b) {
    uint4 v;
    v.x = pk2(a.x, a.y); v.y = pk2(a.z, a.w);
    v.z = pk2(b.x, b.y); v.w = pk2(b.z, b.w);
    *(uint4*)dst = v;
}

// ---------------------------------------------------------------------------
// Weight conversion: fp32 -> bf16 (hi only); also zeroes fix counter
// ---------------------------------------------------------------------------
__global__ __launch_bounds__(256) void conv_w(
    const float* __restrict__ wq, const float* __restrict__ wk,
    u16* __restrict__ qh, u16* __restrict__ kh, int* __restrict__ fix_cnt)
{
    int i = blockIdx.x * 256 + threadIdx.x;
    if (i == 0) *fix_cnt = 0;
    if (i >= D_ * D_) return;
    qh[i] = f2bf_rne(wq[i]);
    kh[i] = f2bf_rne(wk[i]);
}

// ---------------------------------------------------------------------------
// Blocked-transpose fp32 weights for the fixup:
//   wt[(k>>2)*2048 + c*4 + (k&3)] = w[c][k]
// ---------------------------------------------------------------------------
__global__ __launch_bounds__(256) void transp_w(
    const float* __restrict__ wq, const float* __restrict__ wk,
    float* __restrict__ wqt, float* __restrict__ wkt)
{
    __shared__ float tile[64][65];
    const int bi = blockIdx.x;   // c tile
    const int bj = blockIdx.y;   // k tile
    const int t = threadIdx.x;
    const int c0 = bi * 64, k0 = bj * 64;
    const float* src = wq; float* dst = wqt;
#pragma unroll
    for (int m = 0; m < 2; ++m) {
        __syncthreads();
#pragma unroll
        for (int it = 0; it < 4; ++it) {
            int r = it * 16 + (t >> 4);
            int cc = (t & 15) * 4;
            float4 v = *(const float4*)(src + (size_t)(c0 + r) * D_ + k0 + cc);
            tile[r][cc] = v.x; tile[r][cc + 1] = v.y;
            tile[r][cc + 2] = v.z; tile[r][cc + 3] = v.w;
        }
        __syncthreads();
#pragma unroll
        for (int it = 0; it < 4; ++it) {
            int cl = t & 63;
            int kq = it * 4 + (t >> 6);          // local k-quad 0..15
            float4 v;
            v.x = tile[cl][kq * 4 + 0]; v.y = tile[cl][kq * 4 + 1];
            v.z = tile[cl][kq * 4 + 2]; v.w = tile[cl][kq * 4 + 3];
            size_t o = ((size_t)((k0 >> 2) + kq) * 512 + (c0 + cl)) * 4;
            *(float4*)(dst + o) = v;
        }
        src = wk; dst = wkt;
    }
}

// ---------------------------------------------------------------------------
// Shared-A bf16 MFMA kernel: dbuf LDS (1 barrier/step), swizzled chunks
// (pos = c ^ ((row>>1)&3), 2-way max bank aliasing), hw packed cvt.
// part layout: [NCT][B][L][3]
// ---------------------------------------------------------------------------
__global__ __launch_bounds__(256, 2) void qk_mfma(
    const float* __restrict__ h,
    const u16* __restrict__ wqh, const u16* __restrict__ wkh,
    float* __restrict__ part)
{
    const int ct = blockIdx.x, rt = blockIdx.y, b = blockIdx.z;
    const int t = threadIdx.x, wid = t >> 6, lane = t & 63;
    const int l15 = lane & 15, l4 = lane >> 4;

    __shared__ __align__(16) u16 ah[2][4608];   // [buf][row 0..143][32]
    __shared__ float red[4][BM][3];

    // zero pad rows 129..143 of both buffers
    if (t < 240) {
        ((u32*)ah[0])[2064 + t] = 0;
        ((u32*)ah[1])[2064 + t] = 0;
    }

    const int r0 = rt * BM;
    const float* hb = h + (size_t)b * L_ * D_;

    // staging: chunk i -> row = i>>2, c = i&3 (8 floats each);
    // thread t handles i = t and i = t+256; t<4 also i = 512+t (row 128)
    const int row0 = t >> 2, ci = t & 3;
    const float* sp0 = hb + (size_t)(r0 + row0) * D_ + ci * 8;
    const float* sp1 = sp0 + (size_t)64 * D_;
    int r128 = r0 + BM; if (r128 > L_ - 1) r128 = L_ - 1;
    const float* sp2 = hb + (size_t)r128 * D_ + ci * 8;

    const int sw0 = (row0 >> 1) & 3;            // same bits for row0+64
    const int w0 = row0 * 32 + ((ci ^ sw0) * 8);
    const int w1 = (row0 + 64) * 32 + ((ci ^ sw0) * 8);
    const int w2 = 128 * 32 + (ci * 8);         // row 128: swizzle bits = 0

    // B-fragment pointers
    const int colb = ct * 128 + wid * 32;
    const u16* bq0 = wqh + (size_t)(colb + l15) * D_ + l4 * 8;
    const u16* bq1 = bq0 + (size_t)16 * D_;
    const u16* bk0 = wkh + (size_t)(colb + l15) * D_ + l4 * 8;
    const u16* bk1 = bk0 + (size_t)16 * D_;

    // swizzled LDS read offsets
    int aoff[8];
#pragma unroll
    for (int rf = 0; rf < 8; ++rf) {
        int R = rf * 16 + l15;
        aoff[rf] = R * 32 + ((l4 ^ ((R >> 1) & 3)) * 8);
    }
    const int Re = 128 + l15;
    const int aoffE = Re * 32 + ((l4 ^ ((Re >> 1) & 3)) * 8);

    f32x4 accq[8][2], acck[8][2], ackl[2];
    const f32x4 zero = {0.f, 0.f, 0.f, 0.f};
#pragma unroll
    for (int rf = 0; rf < 8; ++rf) {
        accq[rf][0] = zero; accq[rf][1] = zero;
        acck[rf][0] = zero; acck[rf][1] = zero;
    }
    ackl[0] = zero; ackl[1] = zero;

    // prologue: load + stage step 0 into buf 0
    float4 pa0 = *(const float4*)sp0, pb0 = *(const float4*)(sp0 + 4);
    float4 pa1 = *(const float4*)sp1, pb1 = *(const float4*)(sp1 + 4);
    float4 pa2 = {0,0,0,0}, pb2 = {0,0,0,0};
    if (t < 4) { pa2 = *(const float4*)sp2; pb2 = *(const float4*)(sp2 + 4); }
    store_chunk(&ah[0][w0], pa0, pb0);
    store_chunk(&ah[0][w1], pa1, pb1);
    if (t < 4) store_chunk(&ah[0][w2], pa2, pb2);
    __syncthreads();

    int cur = 0;
    for (int s = 0; s < NSTEP; ++s) {
        const int so = s * 32;
        const int sn = (s + 1 < NSTEP ? s + 1 : s) * 32;

        // issue next-step A loads (latency hides under MFMAs)
        pa0 = *(const float4*)(sp0 + sn); pb0 = *(const float4*)(sp0 + sn + 4);
        pa1 = *(const float4*)(sp1 + sn); pb1 = *(const float4*)(sp1 + sn + 4);
        if (t < 4) { pa2 = *(const float4*)(sp2 + sn); pb2 = *(const float4*)(sp2 + sn + 4); }

        // B fragments (L2-resident weights)
        bf16x8 fbq0 = *(const bf16x8*)(bq0 + so);
        bf16x8 fbq1 = *(const bf16x8*)(bq1 + so);
        bf16x8 fbk0 = *(const bf16x8*)(bk0 + so);
        bf16x8 fbk1 = *(const bf16x8*)(bk1 + so);

#pragma unroll
        for (int rf = 0; rf < 8; ++rf) {
            bf16x8 a = *(const bf16x8*)(&ah[cur][aoff[rf]]);
            accq[rf][0] = __builtin_amdgcn_mfma_f32_16x16x32_bf16(a, fbq0, accq[rf][0], 0, 0, 0);
            accq[rf][1] = __builtin_amdgcn_mfma_f32_16x16x32_bf16(a, fbq1, accq[rf][1], 0, 0, 0);
            acck[rf][0] = __builtin_amdgcn_mfma_f32_16x16x32_bf16(a, fbk0, acck[rf][0], 0, 0, 0);
            acck[rf][1] = __builtin_amdgcn_mfma_f32_16x16x32_bf16(a, fbk1, acck[rf][1], 0, 0, 0);
        }
        bf16x8 al = *(const bf16x8*)(&ah[cur][aoffE]);
        ackl[0] = __builtin_amdgcn_mfma_f32_16x16x32_bf16(al, fbk0, ackl[0], 0, 0, 0);
        ackl[1] = __builtin_amdgcn_mfma_f32_16x16x32_bf16(al, fbk1, ackl[1], 0, 0, 0);

        // cvt + stage next step into the other buffer
        store_chunk(&ah[cur ^ 1][w0], pa0, pb0);
        store_chunk(&ah[cur ^ 1][w1], pa1, pb1);
        if (t < 4) store_chunk(&ah[cur ^ 1][w2], pa2, pb2);
        __syncthreads();
        cur ^= 1;
    }

    // epilogue: per-row partials. C/D layout: col=lane&15, row=(lane>>4)*4+reg.
#pragma unroll
    for (int rf = 0; rf < 8; ++rf) {
#pragma unroll
        for (int reg = 0; reg < 4; ++reg) {
            float pq = 0.f, pk = 0.f, pd = 0.f;
#pragma unroll
            for (int cf = 0; cf < 2; ++cf) {
                float q  = accq[rf][cf][reg];
                float kv = acck[rf][cf][reg];
                pq += q * q;
                pk += kv * kv;
                float ksh;
                if (reg < 3) {
                    ksh = acck[rf][cf][reg + 1];
                } else {
                    float up = __shfl(acck[rf][cf][0], (lane + 16) & 63);
                    float nx0 = (rf < 7) ? acck[rf + 1][cf][0] : ackl[cf][0];
                    float nx = __shfl(nx0, l15);
                    ksh = (l4 == 3) ? nx : up;
                }
                pd += q * ksh;
            }
#pragma unroll
            for (int off = 1; off < 16; off <<= 1) {
                pq += __shfl_xor(pq, off);
                pk += __shfl_xor(pk, off);
                pd += __shfl_xor(pd, off);
            }
            if (l15 == 0) {
                int row = rf * 16 + l4 * 4 + reg;
                red[wid][row][0] = pq;
                red[wid][row][1] = pk;
                red[wid][row][2] = pd;
            }
        }
    }
    __syncthreads();
    if (t < BM) {
        float pq = red[0][t][0] + red[1][t][0] + red[2][t][0] + red[3][t][0];
        float pk = red[0][t][1] + red[1][t][1] + red[2][t][1] + red[3][t][1];
        float pd = red[0][t][2] + red[1][t][2] + red[2][t][2] + red[3][t][2];
        size_t o = (((size_t)ct * B_ + b) * L_ + (r0 + t)) * 3;
        part[o + 0] = pq; part[o + 1] = pk; part[o + 2] = pd;
    }
}

// ---------------------------------------------------------------------------
// reduce partials -> p (nk read shifted by one row); flag borderline rows
// ---------------------------------------------------------------------------
__global__ __launch_bounds__(256) void cos_reduce(
    const float* __restrict__ part, float* __restrict__ p,
    int* __restrict__ fix_cnt, int* __restrict__ fix_list)
{
    int idx = blockIdx.x * 256 + threadIdx.x;
    if (idx >= B_ * L_) return;
    int b = idx / L_;
    int tp = idx % L_;
    if (tp == 0) { p[idx] = 1.0f; return; }
    int l = tp - 1;
    float nq = 0.f, nk = 0.f, dt = 0.f;
#pragma unroll
    for (int ct = 0; ct < NCT; ++ct) {
        size_t o = (((size_t)ct * B_ + b) * L_ + l) * 3;
        nq += part[o + 0];
        dt += part[o + 2];
        nk += part[o + 4];        // part[...][l+1][1]
    }
    float qn = sqrtf(nq); if (qn < 1e-12f) qn = 1e-12f;
    float kn = sqrtf(nk); if (kn < 1e-12f) kn = 1e-12f;
    float cs = dt / (qn * kn);
    float pr = 0.5f * (1.0f - cs);
    pr = fminf(fmaxf(pr, 0.0f), 1.0f);
    p[idx] = pr;
    if (fabsf(cs) < FIX_TAU) {
        int slot = atomicAdd(fix_cnt, 1);
        if (slot < MAXFIX) fix_list[slot] = idx;
    }
}

// ---------------------------------------------------------------------------
// fp32 fixup: block = 256 threads, FTILE=4 borderline rows, all 512 cols.
// Software-pipelined weight stream (verified round 6).
// ---------------------------------------------------------------------------
__global__ __launch_bounds__(256) void fixup_main(
    const float* __restrict__ h,
    const float* __restrict__ wqt, const float* __restrict__ wkt,
    const int* __restrict__ fix_cnt, const int* __restrict__ fix_list,
    float* __restrict__ p)
{
    __shared__ float hq[FTILE][D_];
    __shared__ float hk[FTILE][D_];
    __shared__ float red[FTILE][3][4];
    const int t = threadIdx.x, wid = t >> 6, lane = t & 63;
    int n = *fix_cnt; if (n > MAXFIX) n = MAXFIX;
    const int ntiles = (n + FTILE - 1) / FTILE;

    for (int tile = blockIdx.x; tile < ntiles; tile += gridDim.x) {
        __syncthreads();
#pragma unroll
        for (int r = 0; r < FTILE; ++r) {
            int s = tile * FTILE + r;
            int idx = fix_list[s < n ? s : 0];
            int bb = idx >> 13;                  // L_ = 8192
            int tp = idx & (L_ - 1);             // >= 1 for flagged rows
            const float* hr = h + ((size_t)bb * L_ + (tp - 1)) * D_;
            ((float2*)hq[r])[t] = ((const float2*)hr)[t];
            ((float2*)hk[r])[t] = ((const float2*)(hr + D_))[t];
        }
        __syncthreads();

        float qa0[FTILE], qa1[FTILE], ka0[FTILE], ka1[FTILE];
#pragma unroll
        for (int r = 0; r < FTILE; ++r) { qa0[r] = qa1[r] = ka0[r] = ka1[r] = 0.f; }

        // software-pipelined weight stream
        float4 wc0 = *(const float4*)(wqt + ((size_t)0 * 512 + t) * 4);
        float4 wc1 = *(const float4*)(wqt + ((size_t)0 * 512 + t + 256) * 4);
        float4 xc0 = *(const float4*)(wkt + ((size_t)0 * 512 + t) * 4);
        float4 xc1 = *(const float4*)(wkt + ((size_t)0 * 512 + t + 256) * 4);
#pragma unroll 4
        for (int kq = 0; kq < D_ / 4; ++kq) {
            const int kn = (kq + 1) & (D_ / 4 - 1);   // wraps on last iter (harmless)
            float4 wn0 = *(const float4*)(wqt + ((size_t)kn * 512 + t) * 4);
            float4 wn1 = *(const float4*)(wqt + ((size_t)kn * 512 + t + 256) * 4);
            float4 xn0 = *(const float4*)(wkt + ((size_t)kn * 512 + t) * 4);
            float4 xn1 = *(const float4*)(wkt + ((size_t)kn * 512 + t + 256) * 4);
#pragma unroll
            for (int r = 0; r < FTILE; ++r) {
                float4 hv = *(const float4*)(&hq[r][kq * 4]);
                float4 kv = *(const float4*)(&hk[r][kq * 4]);
                qa0[r] += hv.x * wc0.x + hv.y * wc0.y + hv.z * wc0.z + hv.w * wc0.w;
                qa1[r] += hv.x * wc1.x + hv.y * wc1.y + hv.z * wc1.z + hv.w * wc1.w;
                ka0[r] += kv.x * xc0.x + kv.y * xc0.y + kv.z * xc0.z + kv.w * xc0.w;
                ka1[r] += kv.x * xc1.x + kv.y * xc1.y + kv.z * xc1.z + kv.w * xc1.w;
            }
            wc0 = wn0; wc1 = wn1; xc0 = xn0; xc1 = xn1;
        }

#pragma unroll
        for (int r = 0; r < FTILE; ++r) {
            float pq = qa0[r] * qa0[r] + qa1[r] * qa1[r];
            float pk = ka0[r] * ka0[r] + ka1[r] * ka1[r];
            float pd = qa0[r] * ka0[r] + qa1[r] * ka1[r];
#pragma unroll
            for (int off = 1; off < 64; off <<= 1) {
                pq += __shfl_xor(pq, off);
                pk += __shfl_xor(pk, off);
                pd += __shfl_xor(pd, off);
            }
            if (lane == 0) { red[r][0][wid] = pq; red[r][1][wid] = pk; red[r][2][wid] = pd; }
        }
        __syncthreads();
        if (t < FTILE) {
            int s = tile * FTILE + t;
            if (s < n) {
                float nq = red[t][0][0] + red[t][0][1] + red[t][0][2] + red[t][0][3];
                float nk = red[t][1][0] + red[t][1][1] + red[t][1][2] + red[t][1][3];
                float dt = red[t][2][0] + red[t][2][1] + red[t][2][2] + red[t][2][3];
                float qn = sqrtf(nq); if (qn < 1e-12f) qn = 1e-12f;
                float kn = sqrtf(nk); if (kn < 1e-12f) kn = 1e-12f;
                float cs = dt / (qn * kn);
                float pr = 0.5f * (1.0f - cs);
                pr = fminf(fmaxf(pr, 0.0f), 1.0f);
                p[fix_list[s]] = pr;
            }
        }
    }
}

// ---------------------------------------------------------------------------
// EMA scan, float2 per thread, branchless (unchanged)
// ---------------------------------------------------------------------------
__global__ __launch_bounds__(256) void scan_a(
    const float* __restrict__ h, const float* __restrict__ p,
    float* __restrict__ Bc, float* __restrict__ Ac)
{
    const int t = threadIdx.x;
    const int c = blockIdx.x, b = blockIdx.y;
    const int l0 = c * CHUNK;
    const float* pb = p + (size_t)b * L_ + l0;
    const float2* hb = (const float2*)(h + ((size_t)b * L_ + l0) * D_) + t;

    float2 st = {0.f, 0.f};
    float ap = 1.f;
#pragma unroll 4
    for (int i = 0; i < CHUNK; ++i) {
        float pr = pb[i];
        float2 hv = hb[(size_t)i * 256];
        bool sel = pr > 0.5f;
        float a = sel ? 1.f - pr : 1.f;
        float g = sel ? pr : 0.f;
        st.x = a * st.x + g * hv.x;
        st.y = a * st.y + g * hv.y;
        ap *= a;
    }
    ((float2*)Bc)[((size_t)b * NCHUNK + c) * 256 + t] = st;
    if (t == 0) Ac[b * NCHUNK + c] = ap;
}

__global__ __launch_bounds__(256) void scan_b(
    const float* __restrict__ Ac, const float* __restrict__ Bc,
    const float* __restrict__ det, float* __restrict__ carry)
{
    const int t = threadIdx.x;
    const int b = blockIdx.x;
    float2 st = ((const float2*)det)[(size_t)b * 256 + t];
    for (int c = 0; c < NCHUNK; ++c) {
        ((float2*)carry)[((size_t)b * NCHUNK + c) * 256 + t] = st;
        float a = Ac[b * NCHUNK + c];
        float2 bc = ((const float2*)Bc)[((size_t)b * NCHUNK + c) * 256 + t];
        st.x = a * st.x + bc.x;
        st.y = a * st.y + bc.y;
    }
}

__global__ __launch_bounds__(256) void scan_c(
    const float* __restrict__ h, const float* __restrict__ p,
    const float* __restrict__ res, const float* __restrict__ carry,
    float* __restrict__ out)
{
    const int t = threadIdx.x;
    const int c = blockIdx.x, b = blockIdx.y;
    const int l0 = c * CHUNK;
    const float* pb = p + (size_t)b * L_ + l0;
    const size_t base = ((size_t)b * L_ + l0) * 256 + t;   // float2 units
    const float2* hb = (const float2*)h + base;
    const float2* rb = (const float2*)res + base;
    float2* ob = (float2*)out + base;

    float2 st = ((const float2*)carry)[((size_t)b * NCHUNK + c) * 256 + t];
#pragma unroll 4
    for (int i = 0; i < CHUNK; ++i) {
        float pr = pb[i];
        float2 hv = hb[(size_t)i * 256];
        float2 rv = rb[(size_t)i * 256];
        bool sel = pr > 0.5f;
        float a = sel ? 1.f - pr : 1.f;
        float g = sel ? pr : 0.f;
        st.x = a * st.x + g * hv.x;
        st.y = a * st.y + g * hv.y;
        float2 ov; ov.x = rv.x + st.x; ov.y = rv.y + st.y;
        ob[(size_t)i * 256] = ov;
    }
}

// ---------------------------------------------------------------------------
extern "C" void kernel_launch(void* const* d_in, const int* in_sizes, int n_in,
                              void* d_out, int out_size, void* d_ws, size_t ws_size,
                              hipStream_t stream)
{
    const float* h   = (const float*)d_in[0];
    const float* res = (const float*)d_in[1];
    const float* wq  = (const float*)d_in[2];
    const float* wk  = (const float*)d_in[3];
    const float* det = (const float*)d_in[4];
    float* out = (float*)d_out;

    // ws layout (floats)
    float* ws = (float*)d_ws;
    float* part  = ws;                                     // 393216
    float* p     = part + (size_t)NCT * B_ * L_ * 3;       // 32768
    float* Ac    = p + (size_t)B_ * L_;                    // 512
    float* Bc    = Ac + (size_t)B_ * NCHUNK;               // 262144
    float* carry = Bc + (size_t)B_ * NCHUNK * D_;          // 262144
    int*  fix_cnt  = (int*)(carry + (size_t)B_ * NCHUNK * D_);
    int*  fix_list = fix_cnt + 4;                          // MAXFIX ints
    u16* wqh = (u16*)(fix_list + MAXFIX);                  // D*D u16 each
    u16* wkh = wqh + (size_t)D_ * D_;
    float* wqt = (float*)(wkh + (size_t)D_ * D_);          // D*D f32 each
    float* wkt = wqt + (size_t)D_ * D_;

    conv_w<<<(D_ * D_ + 255) / 256, 256, 0, stream>>>(wq, wk, wqh, wkh, fix_cnt);
    transp_w<<<dim3(8, 8), 256, 0, stream>>>(wq, wk, wqt, wkt);
    qk_mfma<<<dim3(NCT, NRT, B_), 256, 0, stream>>>(h, wqh, wkh, part);
    cos_reduce<<<(B_ * L_ + 255) / 256, 256, 0, stream>>>(part, p, fix_cnt, fix_list);
    fixup_main<<<256, 256, 0, stream>>>(h, wqt, wkt, fix_cnt, fix_list, p);
    scan_a<<<dim3(NCHUNK, B_), 256, 0, stream>>>(h, p, Bc, Ac);
    scan_b<<<B_, 256, 0, stream>>>(Ac, Bc, det, carry);
    scan_c<<<dim3(NCHUNK, B_), 256, 0, stream>>>(h, p, res, carry, out);
}

// Round 8
// 213.947 us; speedup vs baseline: 1.0463x; 1.0463x over previous
//
#include <hip/hip_runtime.h>
#include <hip/hip_bf16.h>
#include <math.h>

// Problem constants
#define B_  4
#define L_  8192
#define D_  512

// MFMA GEMM tiling
#define BM   128
#define NCT  4                 // col tiles of 128
#define NRT  (L_ / BM)         // 64
#define NSTEP 16               // K = 512 / 32

// Scan chunking
#define CHUNK 64
#define NCHUNK (L_ / CHUNK)    // 128

#define MAXFIX 16380
#define FIX_TAU 1.0e-3f
#define FTILE 4                // borderline rows per fixup block

typedef short bf16x8 __attribute__((ext_vector_type(8)));
typedef float f32x4 __attribute__((ext_vector_type(4)));
typedef unsigned short u16;
typedef unsigned int u32;

__device__ __forceinline__ u16 f2bf_rne(float f) {
    unsigned u = __float_as_uint(f);
    unsigned r = (u + 0x7FFFu + ((u >> 16) & 1u)) >> 16;
    return (u16)r;
}

// packed fp32x2 -> bf16x2 (hardware v_cvt_pk_bf16_f32, RNE)
__device__ __forceinline__ u32 pk2(float lo, float hi) {
    __hip_bfloat162 v = __float22bfloat162_rn(float2{lo, hi});
    union { __hip_bfloat162 b; u32 u; } cv; cv.b = v;
    return cv.u;
}

__device__ __forceinline__ void store_chunk(u16* dst, float4 a, float4 b) {
    uint4 v;
    v.x = pk2(a.x, a.y); v.y = pk2(a.z, a.w);
    v.z = pk2(b.x, b.y); v.w = pk2(b.z, b.w);
    *(uint4*)dst = v;
}

// ---------------------------------------------------------------------------
// Weight conversion: fp32 -> bf16 (hi only); also zeroes fix counter
// ---------------------------------------------------------------------------
__global__ __launch_bounds__(256) void conv_w(
    const float* __restrict__ wq, const float* __restrict__ wk,
    u16* __restrict__ qh, u16* __restrict__ kh, int* __restrict__ fix_cnt)
{
    int i = blockIdx.x * 256 + threadIdx.x;
    if (i == 0) *fix_cnt = 0;
    if (i >= D_ * D_) return;
    qh[i] = f2bf_rne(wq[i]);
    kh[i] = f2bf_rne(wk[i]);
}

// ---------------------------------------------------------------------------
// Blocked-transpose fp32 weights for the fixup:
//   wt[(k>>2)*2048 + c*4 + (k&3)] = w[c][k]
// ---------------------------------------------------------------------------
__global__ __launch_bounds__(256) void transp_w(
    const float* __restrict__ wq, const float* __restrict__ wk,
    float* __restrict__ wqt, float* __restrict__ wkt)
{
    __shared__ float tile[64][65];
    const int bi = blockIdx.x;   // c tile
    const int bj = blockIdx.y;   // k tile
    const int t = threadIdx.x;
    const int c0 = bi * 64, k0 = bj * 64;
    const float* src = wq; float* dst = wqt;
#pragma unroll
    for (int m = 0; m < 2; ++m) {
        __syncthreads();
#pragma unroll
        for (int it = 0; it < 4; ++it) {
            int r = it * 16 + (t >> 4);
            int cc = (t & 15) * 4;
            float4 v = *(const float4*)(src + (size_t)(c0 + r) * D_ + k0 + cc);
            tile[r][cc] = v.x; tile[r][cc + 1] = v.y;
            tile[r][cc + 2] = v.z; tile[r][cc + 3] = v.w;
        }
        __syncthreads();
#pragma unroll
        for (int it = 0; it < 4; ++it) {
            int cl = t & 63;
            int kq = it * 4 + (t >> 6);          // local k-quad 0..15
            float4 v;
            v.x = tile[cl][kq * 4 + 0]; v.y = tile[cl][kq * 4 + 1];
            v.z = tile[cl][kq * 4 + 2]; v.w = tile[cl][kq * 4 + 3];
            size_t o = ((size_t)((k0 >> 2) + kq) * 512 + (c0 + cl)) * 4;
            *(float4*)(dst + o) = v;
        }
        src = wk; dst = wkt;
    }
}

// ---------------------------------------------------------------------------
// Shared-A bf16 MFMA kernel.
// Round-6 schedule (store-at-top, prefetch consumed a full iteration later),
// round-7 hw packed cvt (done at store site) + conflict-free XOR swizzle
// (chunk ^= (row>>1)&3, both write and read sides).
// part layout: [NCT][B][L][3]
// ---------------------------------------------------------------------------
__global__ __launch_bounds__(256, 2) void qk_mfma(
    const float* __restrict__ h,
    const u16* __restrict__ wqh, const u16* __restrict__ wkh,
    float* __restrict__ part)
{
    const int ct = blockIdx.x, rt = blockIdx.y, b = blockIdx.z;
    const int t = threadIdx.x, wid = t >> 6, lane = t & 63;
    const int l15 = lane & 15, l4 = lane >> 4;

    __shared__ __align__(16) u16 ah[4608];      // [row 0..143][32]
    __shared__ float red[4][BM][3];

    if (t < 240) ((u32*)ah)[2064 + t] = 0;      // zero rows 129..143

    const int r0 = rt * BM;
    const float* hb = h + (size_t)b * L_ * D_;

    // staging: chunk i -> row = i>>2, c = i&3 (8 floats each);
    // thread t handles rows row0 and row0+64; t<4 also row 128
    const int row0 = t >> 2, ci = t & 3;
    const float* sp0 = hb + (size_t)(r0 + row0) * D_ + ci * 8;
    const float* sp1 = sp0 + (size_t)64 * D_;
    int r128 = r0 + BM; if (r128 > L_ - 1) r128 = L_ - 1;
    const float* sp2 = hb + (size_t)r128 * D_ + ci * 8;

    const int sw0 = (row0 >> 1) & 3;            // same bits for row0+64
    const int w0 = row0 * 32 + ((ci ^ sw0) * 8);
    const int w1 = (row0 + 64) * 32 + ((ci ^ sw0) * 8);
    const int w2 = 128 * 32 + (ci * 8);         // row 128: swizzle bits = 0

    // B-fragment pointers
    const int colb = ct * 128 + wid * 32;
    const u16* bq0 = wqh + (size_t)(colb + l15) * D_ + l4 * 8;
    const u16* bq1 = bq0 + (size_t)16 * D_;
    const u16* bk0 = wkh + (size_t)(colb + l15) * D_ + l4 * 8;
    const u16* bk1 = bk0 + (size_t)16 * D_;

    // swizzled LDS read offsets
    int aoff[8];
#pragma unroll
    for (int rf = 0; rf < 8; ++rf) {
        int R = rf * 16 + l15;
        aoff[rf] = R * 32 + ((l4 ^ ((R >> 1) & 3)) * 8);
    }
    const int Re = 128 + l15;
    const int aoffE = Re * 32 + ((l4 ^ ((Re >> 1) & 3)) * 8);

    f32x4 accq[8][2], acck[8][2], ackl[2];
    const f32x4 zero = {0.f, 0.f, 0.f, 0.f};
#pragma unroll
    for (int rf = 0; rf < 8; ++rf) {
        accq[rf][0] = zero; accq[rf][1] = zero;
        acck[rf][0] = zero; acck[rf][1] = zero;
    }
    ackl[0] = zero; ackl[1] = zero;

    // prologue: issue step-0 loads (raw fp32; cvt happens at store site)
    float4 pa0 = *(const float4*)sp0, pb0 = *(const float4*)(sp0 + 4);
    float4 pa1 = *(const float4*)sp1, pb1 = *(const float4*)(sp1 + 4);
    float4 pa2 = {0,0,0,0}, pb2 = {0,0,0,0};
    if (t < 4) { pa2 = *(const float4*)sp2; pb2 = *(const float4*)(sp2 + 4); }

    for (int s = 0; s < NSTEP; ++s) {
        __syncthreads();                 // prior step's LDS reads done
        // cvt + stage (consumes loads issued one full iteration ago)
        store_chunk(&ah[w0], pa0, pb0);
        store_chunk(&ah[w1], pa1, pb1);
        if (t < 4) store_chunk(&ah[w2], pa2, pb2);
        __syncthreads();

        const int so = s * 32;
        // B fragments (L2-resident weights)
        bf16x8 fbq0 = *(const bf16x8*)(bq0 + so);
        bf16x8 fbq1 = *(const bf16x8*)(bq1 + so);
        bf16x8 fbk0 = *(const bf16x8*)(bk0 + so);
        bf16x8 fbk1 = *(const bf16x8*)(bk1 + so);

        // issue next-step A loads; consumed at the top of the NEXT iteration
        const int sn = (s + 1 < NSTEP ? s + 1 : s) * 32;
        pa0 = *(const float4*)(sp0 + sn); pb0 = *(const float4*)(sp0 + sn + 4);
        pa1 = *(const float4*)(sp1 + sn); pb1 = *(const float4*)(sp1 + sn + 4);
        if (t < 4) { pa2 = *(const float4*)(sp2 + sn); pb2 = *(const float4*)(sp2 + sn + 4); }

#pragma unroll
        for (int rf = 0; rf < 8; ++rf) {
            bf16x8 a = *(const bf16x8*)(&ah[aoff[rf]]);
            accq[rf][0] = __builtin_amdgcn_mfma_f32_16x16x32_bf16(a, fbq0, accq[rf][0], 0, 0, 0);
            accq[rf][1] = __builtin_amdgcn_mfma_f32_16x16x32_bf16(a, fbq1, accq[rf][1], 0, 0, 0);
            acck[rf][0] = __builtin_amdgcn_mfma_f32_16x16x32_bf16(a, fbk0, acck[rf][0], 0, 0, 0);
            acck[rf][1] = __builtin_amdgcn_mfma_f32_16x16x32_bf16(a, fbk1, acck[rf][1], 0, 0, 0);
        }
        bf16x8 al = *(const bf16x8*)(&ah[aoffE]);
        ackl[0] = __builtin_amdgcn_mfma_f32_16x16x32_bf16(al, fbk0, ackl[0], 0, 0, 0);
        ackl[1] = __builtin_amdgcn_mfma_f32_16x16x32_bf16(al, fbk1, ackl[1], 0, 0, 0);
    }

    // epilogue: per-row partials. C/D layout: col=lane&15, row=(lane>>4)*4+reg.
#pragma unroll
    for (int rf = 0; rf < 8; ++rf) {
#pragma unroll
        for (int reg = 0; reg < 4; ++reg) {
            float pq = 0.f, pk = 0.f, pd = 0.f;
#pragma unroll
            for (int cf = 0; cf < 2; ++cf) {
                float q  = accq[rf][cf][reg];
                float kv = acck[rf][cf][reg];
                pq += q * q;
                pk += kv * kv;
                float ksh;
                if (reg < 3) {
                    ksh = acck[rf][cf][reg + 1];
                } else {
                    float up = __shfl(acck[rf][cf][0], (lane + 16) & 63);
                    float nx0 = (rf < 7) ? acck[rf + 1][cf][0] : ackl[cf][0];
                    float nx = __shfl(nx0, l15);
                    ksh = (l4 == 3) ? nx : up;
                }
                pd += q * ksh;
            }
#pragma unroll
            for (int off = 1; off < 16; off <<= 1) {
                pq += __shfl_xor(pq, off);
                pk += __shfl_xor(pk, off);
                pd += __shfl_xor(pd, off);
            }
            if (l15 == 0) {
                int row = rf * 16 + l4 * 4 + reg;
                red[wid][row][0] = pq;
                red[wid][row][1] = pk;
                red[wid][row][2] = pd;
            }
        }
    }
    __syncthreads();
    if (t < BM) {
        float pq = red[0][t][0] + red[1][t][0] + red[2][t][0] + red[3][t][0];
        float pk = red[0][t][1] + red[1][t][1] + red[2][t][1] + red[3][t][1];
        float pd = red[0][t][2] + red[1][t][2] + red[2][t][2] + red[3][t][2];
        size_t o = (((size_t)ct * B_ + b) * L_ + (r0 + t)) * 3;
        part[o + 0] = pq; part[o + 1] = pk; part[o + 2] = pd;
    }
}

// ---------------------------------------------------------------------------
// reduce partials -> p (nk read shifted by one row); flag borderline rows
// ---------------------------------------------------------------------------
__global__ __launch_bounds__(256) void cos_reduce(
    const float* __restrict__ part, float* __restrict__ p,
    int* __restrict__ fix_cnt, int* __restrict__ fix_list)
{
    int idx = blockIdx.x * 256 + threadIdx.x;
    if (idx >= B_ * L_) return;
    int b = idx / L_;
    int tp = idx % L_;
    if (tp == 0) { p[idx] = 1.0f; return; }
    int l = tp - 1;
    float nq = 0.f, nk = 0.f, dt = 0.f;
#pragma unroll
    for (int ct = 0; ct < NCT; ++ct) {
        size_t o = (((size_t)ct * B_ + b) * L_ + l) * 3;
        nq += part[o + 0];
        dt += part[o + 2];
        nk += part[o + 4];        // part[...][l+1][1]
    }
    float qn = sqrtf(nq); if (qn < 1e-12f) qn = 1e-12f;
    float kn = sqrtf(nk); if (kn < 1e-12f) kn = 1e-12f;
    float cs = dt / (qn * kn);
    float pr = 0.5f * (1.0f - cs);
    pr = fminf(fmaxf(pr, 0.0f), 1.0f);
    p[idx] = pr;
    if (fabsf(cs) < FIX_TAU) {
        int slot = atomicAdd(fix_cnt, 1);
        if (slot < MAXFIX) fix_list[slot] = idx;
    }
}

// ---------------------------------------------------------------------------
// fp32 fixup: block = 256 threads, FTILE=4 borderline rows, all 512 cols.
// Software-pipelined weight stream (verified round 6).
// ---------------------------------------------------------------------------
__global__ __launch_bounds__(256) void fixup_main(
    const float* __restrict__ h,
    const float* __restrict__ wqt, const float* __restrict__ wkt,
    const int* __restrict__ fix_cnt, const int* __restrict__ fix_list,
    float* __restrict__ p)
{
    __shared__ float hq[FTILE][D_];
    __shared__ float hk[FTILE][D_];
    __shared__ float red[FTILE][3][4];
    const int t = threadIdx.x, wid = t >> 6, lane = t & 63;
    int n = *fix_cnt; if (n > MAXFIX) n = MAXFIX;
    const int ntiles = (n + FTILE - 1) / FTILE;

    for (int tile = blockIdx.x; tile < ntiles; tile += gridDim.x) {
        __syncthreads();
#pragma unroll
        for (int r = 0; r < FTILE; ++r) {
            int s = tile * FTILE + r;
            int idx = fix_list[s < n ? s : 0];
            int bb = idx >> 13;                  // L_ = 8192
            int tp = idx & (L_ - 1);             // >= 1 for flagged rows
            const float* hr = h + ((size_t)bb * L_ + (tp - 1)) * D_;
            ((float2*)hq[r])[t] = ((const float2*)hr)[t];
            ((float2*)hk[r])[t] = ((const float2*)(hr + D_))[t];
        }
        __syncthreads();

        float qa0[FTILE], qa1[FTILE], ka0[FTILE], ka1[FTILE];
#pragma unroll
        for (int r = 0; r < FTILE; ++r) { qa0[r] = qa1[r] = ka0[r] = ka1[r] = 0.f; }

        // software-pipelined weight stream
        float4 wc0 = *(const float4*)(wqt + ((size_t)0 * 512 + t) * 4);
        float4 wc1 = *(const float4*)(wqt + ((size_t)0 * 512 + t + 256) * 4);
        float4 xc0 = *(const float4*)(wkt + ((size_t)0 * 512 + t) * 4);
        float4 xc1 = *(const float4*)(wkt + ((size_t)0 * 512 + t + 256) * 4);
#pragma unroll 4
        for (int kq = 0; kq < D_ / 4; ++kq) {
            const int kn = (kq + 1) & (D_ / 4 - 1);   // wraps on last iter (harmless)
            float4 wn0 = *(const float4*)(wqt + ((size_t)kn * 512 + t) * 4);
            float4 wn1 = *(const float4*)(wqt + ((size_t)kn * 512 + t + 256) * 4);
            float4 xn0 = *(const float4*)(wkt + ((size_t)kn * 512 + t) * 4);
            float4 xn1 = *(const float4*)(wkt + ((size_t)kn * 512 + t + 256) * 4);
#pragma unroll
            for (int r = 0; r < FTILE; ++r) {
                float4 hv = *(const float4*)(&hq[r][kq * 4]);
                float4 kv = *(const float4*)(&hk[r][kq * 4]);
                qa0[r] += hv.x * wc0.x + hv.y * wc0.y + hv.z * wc0.z + hv.w * wc0.w;
                qa1[r] += hv.x * wc1.x + hv.y * wc1.y + hv.z * wc1.z + hv.w * wc1.w;
                ka0[r] += kv.x * xc0.x + kv.y * xc0.y + kv.z * xc0.z + kv.w * xc0.w;
                ka1[r] += kv.x * xc1.x + kv.y * xc1.y + kv.z * xc1.z + kv.w * xc1.w;
            }
            wc0 = wn0; wc1 = wn1; xc0 = xn0; xc1 = xn1;
        }

#pragma unroll
        for (int r = 0; r < FTILE; ++r) {
            float pq = qa0[r] * qa0[r] + qa1[r] * qa1[r];
            float pk = ka0[r] * ka0[r] + ka1[r] * ka1[r];
            float pd = qa0[r] * ka0[r] + qa1[r] * ka1[r];
#pragma unroll
            for (int off = 1; off < 64; off <<= 1) {
                pq += __shfl_xor(pq, off);
                pk += __shfl_xor(pk, off);
                pd += __shfl_xor(pd, off);
            }
            if (lane == 0) { red[r][0][wid] = pq; red[r][1][wid] = pk; red[r][2][wid] = pd; }
        }
        __syncthreads();
        if (t < FTILE) {
            int s = tile * FTILE + t;
            if (s < n) {
                float nq = red[t][0][0] + red[t][0][1] + red[t][0][2] + red[t][0][3];
                float nk = red[t][1][0] + red[t][1][1] + red[t][1][2] + red[t][1][3];
                float dt = red[t][2][0] + red[t][2][1] + red[t][2][2] + red[t][2][3];
                float qn = sqrtf(nq); if (qn < 1e-12f) qn = 1e-12f;
                float kn = sqrtf(nk); if (kn < 1e-12f) kn = 1e-12f;
                float cs = dt / (qn * kn);
                float pr = 0.5f * (1.0f - cs);
                pr = fminf(fmaxf(pr, 0.0f), 1.0f);
                p[fix_list[s]] = pr;
            }
        }
    }
}

// ---------------------------------------------------------------------------
// EMA scan, float2 per thread, branchless
// ---------------------------------------------------------------------------
__global__ __launch_bounds__(256) void scan_a(
    const float* __restrict__ h, const float* __restrict__ p,
    float* __restrict__ Bc, float* __restrict__ Ac)
{
    const int t = threadIdx.x;
    const int c = blockIdx.x, b = blockIdx.y;
    const int l0 = c * CHUNK;
    const float* pb = p + (size_t)b * L_ + l0;
    const float2* hb = (const float2*)(h + ((size_t)b * L_ + l0) * D_) + t;

    float2 st = {0.f, 0.f};
    float ap = 1.f;
#pragma unroll 4
    for (int i = 0; i < CHUNK; ++i) {
        float pr = pb[i];
        float2 hv = hb[(size_t)i * 256];
        bool sel = pr > 0.5f;
        float a = sel ? 1.f - pr : 1.f;
        float g = sel ? pr : 0.f;
        st.x = a * st.x + g * hv.x;
        st.y = a * st.y + g * hv.y;
        ap *= a;
    }
    ((float2*)Bc)[((size_t)b * NCHUNK + c) * 256 + t] = st;
    if (t == 0) Ac[b * NCHUNK + c] = ap;
}

// chunk-aggregate scan, software-pipelined in groups of 4 (latency was serial)
__global__ __launch_bounds__(256) void scan_b(
    const float* __restrict__ Ac, const float* __restrict__ Bc,
    const float* __restrict__ det, float* __restrict__ carry)
{
    const int t = threadIdx.x;
    const int b = blockIdx.x;
    const float* acb = Ac + b * NCHUNK;
    const float2* bcb = (const float2*)Bc + (size_t)b * NCHUNK * 256 + t;
    float2* cb = (float2*)carry + (size_t)b * NCHUNK * 256 + t;
    float2 st = ((const float2*)det)[(size_t)b * 256 + t];

    float a0 = acb[0], a1 = acb[1], a2 = acb[2], a3 = acb[3];
    float2 b0 = bcb[0], b1 = bcb[256], b2 = bcb[512], b3 = bcb[768];
    for (int g = 0; g < NCHUNK / 4; ++g) {
        const int nc = (g + 1 < NCHUNK / 4) ? (g + 1) * 4 : g * 4;
        float an0 = acb[nc], an1 = acb[nc + 1], an2 = acb[nc + 2], an3 = acb[nc + 3];
        float2 bn0 = bcb[(size_t)nc * 256],        bn1 = bcb[(size_t)(nc + 1) * 256];
        float2 bn2 = bcb[(size_t)(nc + 2) * 256],  bn3 = bcb[(size_t)(nc + 3) * 256];
        const size_t c0 = (size_t)g * 4 * 256;
        cb[c0]       = st; st.x = a0 * st.x + b0.x; st.y = a0 * st.y + b0.y;
        cb[c0 + 256] = st; st.x = a1 * st.x + b1.x; st.y = a1 * st.y + b1.y;
        cb[c0 + 512] = st; st.x = a2 * st.x + b2.x; st.y = a2 * st.y + b2.y;
        cb[c0 + 768] = st; st.x = a3 * st.x + b3.x; st.y = a3 * st.y + b3.y;
        a0 = an0; a1 = an1; a2 = an2; a3 = an3;
        b0 = bn0; b1 = bn1; b2 = bn2; b3 = bn3;
    }
}

__global__ __launch_bounds__(256) void scan_c(
    const float* __restrict__ h, const float* __restrict__ p,
    const float* __restrict__ res, const float* __restrict__ carry,
    float* __restrict__ out)
{
    const int t = threadIdx.x;
    const int c = blockIdx.x, b = blockIdx.y;
    const int l0 = c * CHUNK;
    const float* pb = p + (size_t)b * L_ + l0;
    const size_t base = ((size_t)b * L_ + l0) * 256 + t;   // float2 units
    const float2* hb = (const float2*)h + base;
    const float2* rb = (const float2*)res + base;
    float2* ob = (float2*)out + base;

    float2 st = ((const float2*)carry)[((size_t)b * NCHUNK + c) * 256 + t];
#pragma unroll 4
    for (int i = 0; i < CHUNK; ++i) {
        float pr = pb[i];
        float2 hv = hb[(size_t)i * 256];
        float2 rv = rb[(size_t)i * 256];
        bool sel = pr > 0.5f;
        float a = sel ? 1.f - pr : 1.f;
        float g = sel ? pr : 0.f;
        st.x = a * st.x + g * hv.x;
        st.y = a * st.y + g * hv.y;
        float2 ov; ov.x = rv.x + st.x; ov.y = rv.y + st.y;
        ob[(size_t)i * 256] = ov;
    }
}

// ---------------------------------------------------------------------------
extern "C" void kernel_launch(void* const* d_in, const int* in_sizes, int n_in,
                              void* d_out, int out_size, void* d_ws, size_t ws_size,
                              hipStream_t stream)
{
    const float* h   = (const float*)d_in[0];
    const float* res = (const float*)d_in[1];
    const float* wq  = (const float*)d_in[2];
    const float* wk  = (const float*)d_in[3];
    const float* det = (const float*)d_in[4];
    float* out = (float*)d_out;

    // ws layout (floats)
    float* ws = (float*)d_ws;
    float* part  = ws;                                     // 393216
    float* p     = part + (size_t)NCT * B_ * L_ * 3;       // 32768
    float* Ac    = p + (size_t)B_ * L_;                    // 512
    float* Bc    = Ac + (size_t)B_ * NCHUNK;               // 262144
    float* carry = Bc + (size_t)B_ * NCHUNK * D_;          // 262144
    int*  fix_cnt  = (int*)(carry + (size_t)B_ * NCHUNK * D_);
    int*  fix_list = fix_cnt + 4;                          // MAXFIX ints
    u16* wqh = (u16*)(fix_list + MAXFIX);                  // D*D u16 each
    u16* wkh = wqh + (size_t)D_ * D_;
    float* wqt = (float*)(wkh + (size_t)D_ * D_);          // D*D f32 each
    float* wkt = wqt + (size_t)D_ * D_;

    conv_w<<<(D_ * D_ + 255) / 256, 256, 0, stream>>>(wq, wk, wqh, wkh, fix_cnt);
    transp_w<<<dim3(8, 8), 256, 0, stream>>>(wq, wk, wqt, wkt);
    qk_mfma<<<dim3(NCT, NRT, B_), 256, 0, stream>>>(h, wqh, wkh, part);
    cos_reduce<<<(B_ * L_ + 255) / 256, 256, 0, stream>>>(part, p, fix_cnt, fix_list);
    fixup_main<<<256, 256, 0, stream>>>(h, wqt, wkt, fix_cnt, fix_list, p);
    scan_a<<<dim3(NCHUNK, B_), 256, 0, stream>>>(h, p, Bc, Ac);
    scan_b<<<B_, 256, 0, stream>>>(Ac, Bc, det, carry);
    scan_c<<<dim3(NCHUNK, B_), 256, 0, stream>>>(h, p, res, carry, out);
}

// Round 9
// 201.742 us; speedup vs baseline: 1.1095x; 1.0605x over previous
//
#include <hip/hip_runtime.h>
#include <hip/hip_bf16.h>
#include <math.h>

// Problem constants
#define B_  4
#define L_  8192
#define D_  512

// MFMA GEMM tiling
#define BM   128
#define NCT  4                 // col tiles of 128
#define NRT  (L_ / BM)         // 64
#define KW   64                // k floats per stage
#define NSTAGE (D_ / KW)       // 8

// Scan chunking
#define CHUNK 64
#define NCHUNK (L_ / CHUNK)    // 128

#define MAXFIX 16380
#define FIX_TAU 1.0e-3f
#define FTILE 4                // borderline rows per fixup block

typedef short bf16x8 __attribute__((ext_vector_type(8)));
typedef float f32x4 __attribute__((ext_vector_type(4)));
typedef unsigned short u16;
typedef unsigned int u32;

// packed fp32x2 -> bf16x2 (hardware v_cvt_pk_bf16_f32, RNE)
__device__ __forceinline__ u32 pk2(float lo, float hi) {
    __hip_bfloat162 v = __float22bfloat162_rn(float2{lo, hi});
    union { __hip_bfloat162 b; u32 u; } cv; cv.b = v;
    return cv.u;
}

// ---------------------------------------------------------------------------
// prep_w: fused weight prep. Per 64x64 tile of Wq/Wk:
//  - bf16 row-major copy (for MFMA B operand)
//  - fp32 blocked transpose wt[(k>>2)*2048 + c*4 + (k&3)] (for fixup)
// Also zeroes fix counter.
// ---------------------------------------------------------------------------
__global__ __launch_bounds__(256) void prep_w(
    const float* __restrict__ wq, const float* __restrict__ wk,
    u16* __restrict__ qh, u16* __restrict__ kh,
    float* __restrict__ wqt, float* __restrict__ wkt,
    int* __restrict__ fix_cnt)
{
    __shared__ float tile[64][65];
    const int bi = blockIdx.x;   // c tile
    const int bj = blockIdx.y;   // k tile
    const int t = threadIdx.x;
    if (bi == 0 && bj == 0 && t == 0) *fix_cnt = 0;
    const int c0 = bi * 64, k0 = bj * 64;
    const float* src = wq; float* dst = wqt; u16* dsth = qh;
#pragma unroll
    for (int m = 0; m < 2; ++m) {
        __syncthreads();
#pragma unroll
        for (int it = 0; it < 4; ++it) {
            int r = it * 16 + (t >> 4);
            int cc = (t & 15) * 4;
            float4 v = *(const float4*)(src + (size_t)(c0 + r) * D_ + k0 + cc);
            tile[r][cc] = v.x; tile[r][cc + 1] = v.y;
            tile[r][cc + 2] = v.z; tile[r][cc + 3] = v.w;
            uint2 hv; hv.x = pk2(v.x, v.y); hv.y = pk2(v.z, v.w);
            *(uint2*)(dsth + (size_t)(c0 + r) * D_ + k0 + cc) = hv;
        }
        __syncthreads();
#pragma unroll
        for (int it = 0; it < 4; ++it) {
            int cl = t & 63;
            int kq = it * 4 + (t >> 6);          // local k-quad 0..15
            float4 v;
            v.x = tile[cl][kq * 4 + 0]; v.y = tile[cl][kq * 4 + 1];
            v.z = tile[cl][kq * 4 + 2]; v.w = tile[cl][kq * 4 + 3];
            size_t o = ((size_t)((k0 >> 2) + kq) * 512 + (c0 + cl)) * 4;
            *(float4*)(dst + o) = v;
        }
        src = wk; dst = wkt; dsth = kh;
    }
}

// ---------------------------------------------------------------------------
// Shared-A bf16 MFMA kernel, round-9 structure:
//  - XCD swizzle: ct-siblings share one XCD's L2 (h fetched ~once)
//  - KW=64 stages (8 barrier-pairs), B frags for both halves issued early
//  - coalesced A staging (16-lane contiguous 256B segments), 1-stage prefetch
//  - granule-XOR LDS swizzle, conflict-free write & read
// part layout: [NCT][B][L][3]; epilogue identical to verified rounds.
// ---------------------------------------------------------------------------
__global__ __launch_bounds__(256, 2) void qk_mfma(
    const float* __restrict__ h,
    const u16* __restrict__ wqh, const u16* __restrict__ wkh,
    float* __restrict__ part)
{
    const int bid = blockIdx.x;
    const int swz = (bid & 7) * 128 + (bid >> 3);    // bijective, 1024%8==0
    const int ct = swz & 3, rt = (swz >> 2) & 63, b = swz >> 8;
    const int t = threadIdx.x, wid = t >> 6, lane = t & 63;
    const int l15 = lane & 15, l4 = lane >> 4;

    __shared__ __align__(16) u16 ah[129 * 64];       // [row 0..128][64 bf16]
    __shared__ float red[4][BM][3];

    const int r0 = rt * BM;
    const float* hb = h + (size_t)b * L_ * D_;

    // A staging: fp32 granule q=t&15 (4 floats), rows tr+16j (j=0..7)
    const int tr = t >> 4, q = t & 15;
    const float* gp = hb + (size_t)(r0 + tr) * D_ + q * 4;
    const int re = (r0 + BM > L_ - 1) ? (L_ - 1) : (r0 + BM);
    const float* gpe = hb + (size_t)re * D_ + q * 4;          // t<16 (q=t)
    const int dbase = tr * 64 + (((q >> 1) ^ (tr & 7)) * 8) + ((q & 1) * 4);
    const int dE = 128 * 64 + ((t >> 1) * 8) + ((t & 1) * 4);  // t<16

    // B-fragment pointers
    const int colb = ct * 128 + wid * 32;
    const u16* bq0 = wqh + (size_t)(colb + l15) * D_ + l4 * 8;
    const u16* bq1 = bq0 + (size_t)16 * D_;
    const u16* bk0 = wkh + (size_t)(colb + l15) * D_ + l4 * 8;
    const u16* bk1 = bk0 + (size_t)16 * D_;

    // LDS read offsets (kk=0); kk=1 -> ^32 (granule-XOR swizzle)
    int aoff[8];
#pragma unroll
    for (int rf = 0; rf < 8; ++rf) {
        int R = rf * 16 + l15;
        aoff[rf] = R * 64 + ((l4 ^ (R & 7)) * 8);
    }
    const int aoffE = 128 * 64 + l4 * 8;             // row 128 (row&7 == 0)

    f32x4 accq[8][2], acck[8][2], ackl[2];
    const f32x4 zero = {0.f, 0.f, 0.f, 0.f};
#pragma unroll
    for (int rf = 0; rf < 8; ++rf) {
        accq[rf][0] = zero; accq[rf][1] = zero;
        acck[rf][0] = zero; acck[rf][1] = zero;
    }
    ackl[0] = zero; ackl[1] = zero;

    float4 A0, A1, A2, A3, A4, A5, A6, A7;
    float4 AE = {0.f, 0.f, 0.f, 0.f};

#define LOADA(S) do { const int _o = (S) * KW;                      \
    A0 = *(const float4*)(gp + _o);                                 \
    A1 = *(const float4*)(gp + _o + 8192);                          \
    A2 = *(const float4*)(gp + _o + 16384);                         \
    A3 = *(const float4*)(gp + _o + 24576);                         \
    A4 = *(const float4*)(gp + _o + 32768);                         \
    A5 = *(const float4*)(gp + _o + 40960);                         \
    A6 = *(const float4*)(gp + _o + 49152);                         \
    A7 = *(const float4*)(gp + _o + 57344);                         \
    if (t < 16) AE = *(const float4*)(gpe + _o); } while (0)

#define ST1(J, AV) { uint2 _h; _h.x = pk2(AV.x, AV.y); _h.y = pk2(AV.z, AV.w); \
    *(uint2*)(&ah[dbase + (J) * 1024]) = _h; }

    LOADA(0);
    for (int s = 0; s < NSTAGE; ++s) {
        __syncthreads();                 // prior stage's LDS readers done
        ST1(0, A0) ST1(1, A1) ST1(2, A2) ST1(3, A3)
        ST1(4, A4) ST1(5, A5) ST1(6, A6) ST1(7, A7)
        if (t < 16) { uint2 _h; _h.x = pk2(AE.x, AE.y); _h.y = pk2(AE.z, AE.w);
                      *(uint2*)(&ah[dE]) = _h; }

        // B fragments for BOTH 32-k halves, issued before the barrier
        const int so = s * KW;
        bf16x8 q00 = *(const bf16x8*)(bq0 + so);
        bf16x8 q01 = *(const bf16x8*)(bq0 + so + 32);
        bf16x8 q10 = *(const bf16x8*)(bq1 + so);
        bf16x8 q11 = *(const bf16x8*)(bq1 + so + 32);
        bf16x8 k00 = *(const bf16x8*)(bk0 + so);
        bf16x8 k01 = *(const bf16x8*)(bk0 + so + 32);
        bf16x8 k10 = *(const bf16x8*)(bk1 + so);
        bf16x8 k11 = *(const bf16x8*)(bk1 + so + 32);

        // prefetch next stage's A (consumed at next stage's store site)
        if (s + 1 < NSTAGE) LOADA(s + 1);
        __syncthreads();                 // LDS tile ready

#pragma unroll
        for (int kk = 0; kk < 2; ++kk) {
            bf16x8 fq0 = kk ? q01 : q00;
            bf16x8 fq1 = kk ? q11 : q10;
            bf16x8 fk0 = kk ? k01 : k00;
            bf16x8 fk1 = kk ? k11 : k10;
#pragma unroll
            for (int rf = 0; rf < 8; ++rf) {
                bf16x8 a = *(const bf16x8*)(&ah[aoff[rf] ^ (kk * 32)]);
                accq[rf][0] = __builtin_amdgcn_mfma_f32_16x16x32_bf16(a, fq0, accq[rf][0], 0, 0, 0);
                accq[rf][1] = __builtin_amdgcn_mfma_f32_16x16x32_bf16(a, fq1, accq[rf][1], 0, 0, 0);
                acck[rf][0] = __builtin_amdgcn_mfma_f32_16x16x32_bf16(a, fk0, acck[rf][0], 0, 0, 0);
                acck[rf][1] = __builtin_amdgcn_mfma_f32_16x16x32_bf16(a, fk1, acck[rf][1], 0, 0, 0);
            }
            bf16x8 al = *(const bf16x8*)(&ah[aoffE ^ (kk * 32)]);
            ackl[0] = __builtin_amdgcn_mfma_f32_16x16x32_bf16(al, fk0, ackl[0], 0, 0, 0);
            ackl[1] = __builtin_amdgcn_mfma_f32_16x16x32_bf16(al, fk1, ackl[1], 0, 0, 0);
        }
    }
#undef LOADA
#undef ST1

    // epilogue: per-row partials. C/D layout: col=lane&15, row=(lane>>4)*4+reg.
#pragma unroll
    for (int rf = 0; rf < 8; ++rf) {
#pragma unroll
        for (int reg = 0; reg < 4; ++reg) {
            float pq = 0.f, pk = 0.f, pd = 0.f;
#pragma unroll
            for (int cf = 0; cf < 2; ++cf) {
                float qv = accq[rf][cf][reg];
                float kv = acck[rf][cf][reg];
                pq += qv * qv;
                pk += kv * kv;
                float ksh;
                if (reg < 3) {
                    ksh = acck[rf][cf][reg + 1];
                } else {
                    float up = __shfl(acck[rf][cf][0], (lane + 16) & 63);
                    float nx0 = (rf < 7) ? acck[rf + 1][cf][0] : ackl[cf][0];
                    float nx = __shfl(nx0, l15);
                    ksh = (l4 == 3) ? nx : up;
                }
                pd += qv * ksh;
            }
#pragma unroll
            for (int off = 1; off < 16; off <<= 1) {
                pq += __shfl_xor(pq, off);
                pk += __shfl_xor(pk, off);
                pd += __shfl_xor(pd, off);
            }
            if (l15 == 0) {
                int row = rf * 16 + l4 * 4 + reg;
                red[wid][row][0] = pq;
                red[wid][row][1] = pk;
                red[wid][row][2] = pd;
            }
        }
    }
    __syncthreads();
    if (t < BM) {
        float pq = red[0][t][0] + red[1][t][0] + red[2][t][0] + red[3][t][0];
        float pk = red[0][t][1] + red[1][t][1] + red[2][t][1] + red[3][t][1];
        float pd = red[0][t][2] + red[1][t][2] + red[2][t][2] + red[3][t][2];
        size_t o = (((size_t)ct * B_ + b) * L_ + (r0 + t)) * 3;
        part[o + 0] = pq; part[o + 1] = pk; part[o + 2] = pd;
    }
}

// ---------------------------------------------------------------------------
// reduce partials -> p (nk read shifted by one row); flag borderline rows
// ---------------------------------------------------------------------------
__global__ __launch_bounds__(256) void cos_reduce(
    const float* __restrict__ part, float* __restrict__ p,
    int* __restrict__ fix_cnt, int* __restrict__ fix_list)
{
    int idx = blockIdx.x * 256 + threadIdx.x;
    if (idx >= B_ * L_) return;
    int b = idx / L_;
    int tp = idx % L_;
    if (tp == 0) { p[idx] = 1.0f; return; }
    int l = tp - 1;
    float nq = 0.f, nk = 0.f, dt = 0.f;
#pragma unroll
    for (int ct = 0; ct < NCT; ++ct) {
        size_t o = (((size_t)ct * B_ + b) * L_ + l) * 3;
        nq += part[o + 0];
        dt += part[o + 2];
        nk += part[o + 4];        // part[...][l+1][1]
    }
    float qn = sqrtf(nq); if (qn < 1e-12f) qn = 1e-12f;
    float kn = sqrtf(nk); if (kn < 1e-12f) kn = 1e-12f;
    float cs = dt / (qn * kn);
    float pr = 0.5f * (1.0f - cs);
    pr = fminf(fmaxf(pr, 0.0f), 1.0f);
    p[idx] = pr;
    if (fabsf(cs) < FIX_TAU) {
        int slot = atomicAdd(fix_cnt, 1);
        if (slot < MAXFIX) fix_list[slot] = idx;
    }
}

// ---------------------------------------------------------------------------
// fp32 fixup: block = 256 threads, FTILE=4 borderline rows, all 512 cols.
// Software-pipelined weight stream (verified round 6).
// ---------------------------------------------------------------------------
__global__ __launch_bounds__(256) void fixup_main(
    const float* __restrict__ h,
    const float* __restrict__ wqt, const float* __restrict__ wkt,
    const int* __restrict__ fix_cnt, const int* __restrict__ fix_list,
    float* __restrict__ p)
{
    __shared__ float hq[FTILE][D_];
    __shared__ float hk[FTILE][D_];
    __shared__ float red[FTILE][3][4];
    const int t = threadIdx.x, wid = t >> 6, lane = t & 63;
    int n = *fix_cnt; if (n > MAXFIX) n = MAXFIX;
    const int ntiles = (n + FTILE - 1) / FTILE;

    for (int tile = blockIdx.x; tile < ntiles; tile += gridDim.x) {
        __syncthreads();
#pragma unroll
        for (int r = 0; r < FTILE; ++r) {
            int s = tile * FTILE + r;
            int idx = fix_list[s < n ? s : 0];
            int bb = idx >> 13;                  // L_ = 8192
            int tp = idx & (L_ - 1);             // >= 1 for flagged rows
            const float* hr = h + ((size_t)bb * L_ + (tp - 1)) * D_;
            ((float2*)hq[r])[t] = ((const float2*)hr)[t];
            ((float2*)hk[r])[t] = ((const float2*)(hr + D_))[t];
        }
        __syncthreads();

        float qa0[FTILE], qa1[FTILE], ka0[FTILE], ka1[FTILE];
#pragma unroll
        for (int r = 0; r < FTILE; ++r) { qa0[r] = qa1[r] = ka0[r] = ka1[r] = 0.f; }

        float4 wc0 = *(const float4*)(wqt + ((size_t)0 * 512 + t) * 4);
        float4 wc1 = *(const float4*)(wqt + ((size_t)0 * 512 + t + 256) * 4);
        float4 xc0 = *(const float4*)(wkt + ((size_t)0 * 512 + t) * 4);
        float4 xc1 = *(const float4*)(wkt + ((size_t)0 * 512 + t + 256) * 4);
#pragma unroll 4
        for (int kq = 0; kq < D_ / 4; ++kq) {
            const int kn = (kq + 1) & (D_ / 4 - 1);
            float4 wn0 = *(const float4*)(wqt + ((size_t)kn * 512 + t) * 4);
            float4 wn1 = *(const float4*)(wqt + ((size_t)kn * 512 + t + 256) * 4);
            float4 xn0 = *(const float4*)(wkt + ((size_t)kn * 512 + t) * 4);
            float4 xn1 = *(const float4*)(wkt + ((size_t)kn * 512 + t + 256) * 4);
#pragma unroll
            for (int r = 0; r < FTILE; ++r) {
                float4 hv = *(const float4*)(&hq[r][kq * 4]);
                float4 kv = *(const float4*)(&hk[r][kq * 4]);
                qa0[r] += hv.x * wc0.x + hv.y * wc0.y + hv.z * wc0.z + hv.w * wc0.w;
                qa1[r] += hv.x * wc1.x + hv.y * wc1.y + hv.z * wc1.z + hv.w * wc1.w;
                ka0[r] += kv.x * xc0.x + kv.y * xc0.y + kv.z * xc0.z + kv.w * xc0.w;
                ka1[r] += kv.x * xc1.x + kv.y * xc1.y + kv.z * xc1.z + kv.w * xc1.w;
            }
            wc0 = wn0; wc1 = wn1; xc0 = xn0; xc1 = xn1;
        }

#pragma unroll
        for (int r = 0; r < FTILE; ++r) {
            float pq = qa0[r] * qa0[r] + qa1[r] * qa1[r];
            float pk = ka0[r] * ka0[r] + ka1[r] * ka1[r];
            float pd = qa0[r] * ka0[r] + qa1[r] * ka1[r];
#pragma unroll
            for (int off = 1; off < 64; off <<= 1) {
                pq += __shfl_xor(pq, off);
                pk += __shfl_xor(pk, off);
                pd += __shfl_xor(pd, off);
            }
            if (lane == 0) { red[r][0][wid] = pq; red[r][1][wid] = pk; red[r][2][wid] = pd; }
        }
        __syncthreads();
        if (t < FTILE) {
            int s = tile * FTILE + t;
            if (s < n) {
                float nq = red[t][0][0] + red[t][0][1] + red[t][0][2] + red[t][0][3];
                float nk = red[t][1][0] + red[t][1][1] + red[t][1][2] + red[t][1][3];
                float dt = red[t][2][0] + red[t][2][1] + red[t][2][2] + red[t][2][3];
                float qn = sqrtf(nq); if (qn < 1e-12f) qn = 1e-12f;
                float kn = sqrtf(nk); if (kn < 1e-12f) kn = 1e-12f;
                float cs = dt / (qn * kn);
                float pr = 0.5f * (1.0f - cs);
                pr = fminf(fmaxf(pr, 0.0f), 1.0f);
                p[fix_list[s]] = pr;
            }
        }
    }
}

// ---------------------------------------------------------------------------
// EMA scan, float2 per thread, branchless
// ---------------------------------------------------------------------------
__global__ __launch_bounds__(256) void scan_a(
    const float* __restrict__ h, const float* __restrict__ p,
    float* __restrict__ Bc, float* __restrict__ Ac)
{
    const int t = threadIdx.x;
    const int c = blockIdx.x, b = blockIdx.y;
    const int l0 = c * CHUNK;
    const float* pb = p + (size_t)b * L_ + l0;
    const float2* hb = (const float2*)(h + ((size_t)b * L_ + l0) * D_) + t;

    float2 st = {0.f, 0.f};
    float ap = 1.f;
#pragma unroll 4
    for (int i = 0; i < CHUNK; ++i) {
        float pr = pb[i];
        float2 hv = hb[(size_t)i * 256];
        bool sel = pr > 0.5f;
        float a = sel ? 1.f - pr : 1.f;
        float g = sel ? pr : 0.f;
        st.x = a * st.x + g * hv.x;
        st.y = a * st.y + g * hv.y;
        ap *= a;
    }
    ((float2*)Bc)[((size_t)b * NCHUNK + c) * 256 + t] = st;
    if (t == 0) Ac[b * NCHUNK + c] = ap;
}

// chunk-aggregate scan, software-pipelined in groups of 4
__global__ __launch_bounds__(256) void scan_b(
    const float* __restrict__ Ac, const float* __restrict__ Bc,
    const float* __restrict__ det, float* __restrict__ carry)
{
    const int t = threadIdx.x;
    const int b = blockIdx.x;
    const float* acb = Ac + b * NCHUNK;
    const float2* bcb = (const float2*)Bc + (size_t)b * NCHUNK * 256 + t;
    float2* cb = (float2*)carry + (size_t)b * NCHUNK * 256 + t;
    float2 st = ((const float2*)det)[(size_t)b * 256 + t];

    float a0 = acb[0], a1 = acb[1], a2 = acb[2], a3 = acb[3];
    float2 b0 = bcb[0], b1 = bcb[256], b2 = bcb[512], b3 = bcb[768];
    for (int g = 0; g < NCHUNK / 4; ++g) {
        const int nc = (g + 1 < NCHUNK / 4) ? (g + 1) * 4 : g * 4;
        float an0 = acb[nc], an1 = acb[nc + 1], an2 = acb[nc + 2], an3 = acb[nc + 3];
        float2 bn0 = bcb[(size_t)nc * 256],        bn1 = bcb[(size_t)(nc + 1) * 256];
        float2 bn2 = bcb[(size_t)(nc + 2) * 256],  bn3 = bcb[(size_t)(nc + 3) * 256];
        const size_t c0 = (size_t)g * 4 * 256;
        cb[c0]       = st; st.x = a0 * st.x + b0.x; st.y = a0 * st.y + b0.y;
        cb[c0 + 256] = st; st.x = a1 * st.x + b1.x; st.y = a1 * st.y + b1.y;
        cb[c0 + 512] = st; st.x = a2 * st.x + b2.x; st.y = a2 * st.y + b2.y;
        cb[c0 + 768] = st; st.x = a3 * st.x + b3.x; st.y = a3 * st.y + b3.y;
        a0 = an0; a1 = an1; a2 = an2; a3 = an3;
        b0 = bn0; b1 = bn1; b2 = bn2; b3 = bn3;
    }
}

__global__ __launch_bounds__(256) void scan_c(
    const float* __restrict__ h, const float* __restrict__ p,
    const float* __restrict__ res, const float* __restrict__ carry,
    float* __restrict__ out)
{
    const int t = threadIdx.x;
    const int c = blockIdx.x, b = blockIdx.y;
    const int l0 = c * CHUNK;
    const float* pb = p + (size_t)b * L_ + l0;
    const size_t base = ((size_t)b * L_ + l0) * 256 + t;   // float2 units
    const float2* hb = (const float2*)h + base;
    const float2* rb = (const float2*)res + base;
    float2* ob = (float2*)out + base;

    float2 st = ((const float2*)carry)[((size_t)b * NCHUNK + c) * 256 + t];
#pragma unroll 4
    for (int i = 0; i < CHUNK; ++i) {
        float pr = pb[i];
        float2 hv = hb[(size_t)i * 256];
        float2 rv = rb[(size_t)i * 256];
        bool sel = pr > 0.5f;
        float a = sel ? 1.f - pr : 1.f;
        float g = sel ? pr : 0.f;
        st.x = a * st.x + g * hv.x;
        st.y = a * st.y + g * hv.y;
        float2 ov; ov.x = rv.x + st.x; ov.y = rv.y + st.y;
        ob[(size_t)i * 256] = ov;
    }
}

// ---------------------------------------------------------------------------
extern "C" void kernel_launch(void* const* d_in, const int* in_sizes, int n_in,
                              void* d_out, int out_size, void* d_ws, size_t ws_size,
                              hipStream_t stream)
{
    const float* h   = (const float*)d_in[0];
    const float* res = (const float*)d_in[1];
    const float* wq  = (const float*)d_in[2];
    const float* wk  = (const float*)d_in[3];
    const float* det = (const float*)d_in[4];
    float* out = (float*)d_out;

    // ws layout (floats)
    float* ws = (float*)d_ws;
    float* part  = ws;                                     // 393216
    float* p     = part + (size_t)NCT * B_ * L_ * 3;       // 32768
    float* Ac    = p + (size_t)B_ * L_;                    // 512
    float* Bc    = Ac + (size_t)B_ * NCHUNK;               // 262144
    float* carry = Bc + (size_t)B_ * NCHUNK * D_;          // 262144
    int*  fix_cnt  = (int*)(carry + (size_t)B_ * NCHUNK * D_);
    int*  fix_list = fix_cnt + 4;                          // MAXFIX ints
    u16* wqh = (u16*)(fix_list + MAXFIX);                  // D*D u16 each
    u16* wkh = wqh + (size_t)D_ * D_;
    float* wqt = (float*)(wkh + (size_t)D_ * D_);          // D*D f32 each
    float* wkt = wqt + (size_t)D_ * D_;

    prep_w<<<dim3(8, 8), 256, 0, stream>>>(wq, wk, wqh, wkh, wqt, wkt, fix_cnt);
    qk_mfma<<<NCT * NRT * B_, 256, 0, stream>>>(h, wqh, wkh, part);
    cos_reduce<<<(B_ * L_ + 255) / 256, 256, 0, stream>>>(part, p, fix_cnt, fix_list);
    fixup_main<<<256, 256, 0, stream>>>(h, wqt, wkt, fix_cnt, fix_list, p);
    scan_a<<<dim3(NCHUNK, B_), 256, 0, stream>>>(h, p, Bc, Ac);
    scan_b<<<B_, 256, 0, stream>>>(Ac, Bc, det, carry);
    scan_c<<<dim3(NCHUNK, B_), 256, 0, stream>>>(h, p, res, carry, out);
}